// Round 1
// baseline (126.993 us; speedup 1.0000x reference)
//
#include <hip/hip_runtime.h>

// Periodic radius graph: out[i][j][k] = |(frac[j]-frac[i]+off[k]) @ cell|
// masked to (d2 > 1e-12 && d < 5.0), else 0. N=1024, 27 images.
// 113.2 MB fp32 output -> write-BW bound, floor ~18 us at 6.4 TB/s.
//
// This version: direct-store, no LDS, no barrier. One thread per output
// float4 (4 consecutive elements of the flat [pair][image] array). Each
// thread maps element->(pair, k) via one magic-div by 27; a float4 spans at
// most 2 pairs (only when k0 >= 24). Stores are perfectly coalesced
// (1 KB contiguous per wave store instruction) and spread uniformly across
// the kernel lifetime instead of bunched behind a block-wide barrier.
// No LDS -> occupancy rises from 20/32 to 32/32 waves/CU.
//
// Numerics: d2 expression/order identical to the bit-exact kernel
// (absmax 0.0). Offsets derived from runtime k as exact ints then
// cvt_f32 -> exactly -1.0f/0.0f/1.0f, same bits as the old compile-time
// constants. Mask from d2 only (d2 < 25.0f === sqrt(d2) < 5.0f); value
// from raw v_sqrt_f32 as before.

#define NATOMS 1024
#define NIMG 27
#define NPAIRS (NATOMS * NATOMS)                 // 1048576
#define TOTAL_FLOATS (NPAIRS * NIMG)             // 28311552
#define TOTAL_F4 (TOTAL_FLOATS / 4)              // 7077888
#define THREADS 256

__global__ __launch_bounds__(256) void PeriodicRadiusGraph_kernel(
    const float* __restrict__ frac,   // [1024, 3]
    const float* __restrict__ cell,   // [3, 3]
    float* __restrict__ out)          // [1024, 1024, 27] flat
{
    const unsigned f4 = blockIdx.x * THREADS + threadIdx.x;  // float4 index
    const unsigned e0 = f4 * 4u;                             // first element
    const unsigned p0 = e0 / 27u;                            // magic-div (compiler)
    const unsigned k0 = e0 - p0 * 27u;

    // cell rows (uniform across the grid; L1 broadcast)
    const float c00 = cell[0], c01 = cell[1], c02 = cell[2];
    const float c10 = cell[3], c11 = cell[4], c12 = cell[5];
    const float c20 = cell[6], c21 = cell[7], c22 = cell[8];

    // Pair A = p0; pair B = p0+1 (clamped — only consumed when k0 >= 24,
    // and the last float4 of the grid has k0 = 23, so the clamp is just
    // out-of-bounds safety for the unconditional loads).
    const unsigned pA = p0;
    const unsigned pB = (p0 + 1u < (unsigned)NPAIRS) ? (p0 + 1u) : p0;

    const unsigned jA = pA & (NATOMS - 1u), iA = pA >> 10;
    const unsigned jB = pB & (NATOMS - 1u), iB = pB >> 10;

    // (fj - fi) — same order as the reference; "+ off" happens per element.
    const float dfxA = frac[3u * jA + 0u] - frac[3u * iA + 0u];
    const float dfyA = frac[3u * jA + 1u] - frac[3u * iA + 1u];
    const float dfzA = frac[3u * jA + 2u] - frac[3u * iA + 2u];
    const float dfxB = frac[3u * jB + 0u] - frac[3u * iB + 0u];
    const float dfyB = frac[3u * jB + 1u] - frac[3u * iB + 1u];
    const float dfzB = frac[3u * jB + 2u] - frac[3u * iB + 2u];

    float r[4];
#pragma unroll
    for (int u = 0; u < 4; ++u) {
        const unsigned ku = k0 + (unsigned)u;
        const bool cross = (ku >= 27u);
        const unsigned k = cross ? (ku - 27u) : ku;

        const float dfx = cross ? dfxB : dfxA;
        const float dfy = cross ? dfyB : dfyA;
        const float dfz = cross ? dfzB : dfzA;

        // meshgrid(indexing="ij"): (k/9, (k/3)%3, k%3) - 1, runtime k < 27.
        // k/3 = (k*11)>>5 and k/9 = (k*57)>>9 are exact for k < 32.
        const unsigned k3 = (k * 11u) >> 5;
        const unsigned k9 = (k * 57u) >> 9;
        const float ox = (float)((int)k9 - 1);
        const float oy = (float)((int)(k3 - 3u * k9) - 1);
        const float oz = (float)((int)(k - 3u * k3) - 1);

        const float fx = dfx + ox;
        const float fy = dfy + oy;
        const float fz = dfz + oz;

        const float vx = fx * c00 + fy * c10 + fz * c20;
        const float vy = fx * c01 + fy * c11 + fz * c21;
        const float vz = fx * c02 + fy * c12 + fz * c22;

        const float d2 = vx * vx + vy * vy + vz * vz;
        const float d  = __builtin_amdgcn_sqrtf(d2);
        r[u] = (d2 > 1e-12f && d2 < 25.0f) ? d : 0.0f;
    }

    float4 o;
    o.x = r[0]; o.y = r[1]; o.z = r[2]; o.w = r[3];
    ((float4*)out)[f4] = o;  // coalesced: 1 KB contiguous per wave store
}

extern "C" void kernel_launch(void* const* d_in, const int* in_sizes, int n_in,
                              void* d_out, int out_size, void* d_ws, size_t ws_size,
                              hipStream_t stream) {
    const float* frac = (const float*)d_in[0];
    const float* cell = (const float*)d_in[1];
    float* out = (float*)d_out;

    const int grid = TOTAL_F4 / THREADS;  // 27648 blocks, exact
    PeriodicRadiusGraph_kernel<<<grid, THREADS, 0, stream>>>(frac, cell, out);
}

// Round 3
// 122.752 us; speedup vs baseline: 1.0345x; 1.0345x over previous
//
#include <hip/hip_runtime.h>

// Periodic radius graph: out[i][j][k] = |(frac[j]-frac[i]+off[k]) @ cell|
// masked to (d2 > 1e-12 && d < 5.0), else 0. N=1024, 27 images.
// 113.2 MB fp32 output -> write-BW bound, floor ~18 us at 6.4 TB/s.
//
// Structure: round-0 kernel (best measured: 118.4 us dur_us). One thread per
// (i,j) pair, k unrolled, LDS staging (stride 27 dwords, coprime with 32
// banks -> 2-way=free), coalesced float4 write-out.
//
// SINGLE CHANGE vs round-0: write-out uses __builtin_nontemporal_store
// (global_store_dwordx4 ... nt). Rationale: the timed iteration carries
// 540 MB of HBM writes (432 MB harness poison fill + our 108 MB). The fill's
// dirty MALL backlog is still draining when we start; normal cached stores
// serialize behind dirty-line eviction (both prior kernels plateau at
// ~2.4 TB/s effective). nt bypasses L2/MALL write-allocate so our stream
// interleaves with the drain instead of evicting into it.
//
// Round-2 compile fix: __builtin_nontemporal_store requires a clang vector
// type, not HIP's float4 class -> use ext_vector_type(4) float (same 16-B
// layout, same dwordx4 instruction).
//
// Numerics: identical to round-0 (absmax 0.0). nt changes cache policy only,
// not values.

#define NATOMS 1024
#define NIMG 27
#define PAIRS_PER_BLOCK 256
#define FLOATS_PER_BLOCK (PAIRS_PER_BLOCK * NIMG)   // 6912 floats = 27648 B LDS
#define VEC4_PER_BLOCK (FLOATS_PER_BLOCK / 4)       // 1728

typedef float f32x4 __attribute__((ext_vector_type(4)));

__global__ __launch_bounds__(256) void PeriodicRadiusGraph_kernel(
    const float* __restrict__ frac,   // [1024, 3]
    const float* __restrict__ cell,   // [3, 3]
    float* __restrict__ out)          // [1024, 1024, 27] flat
{
    __shared__ float tile[FLOATS_PER_BLOCK];

    const unsigned t = threadIdx.x;
    const unsigned q = blockIdx.x * PAIRS_PER_BLOCK + t;  // pair index i*1024 + j
    const unsigned j = q & (NATOMS - 1u);
    const unsigned i = q >> 10;                           // uniform within block

    // cell rows (wave-uniform -> scalar loads)
    const float c00 = cell[0], c01 = cell[1], c02 = cell[2];
    const float c10 = cell[3], c11 = cell[4], c12 = cell[5];
    const float c20 = cell[6], c21 = cell[7], c22 = cell[8];

    const float fix = frac[3u * i + 0u], fiy = frac[3u * i + 1u], fiz = frac[3u * i + 2u];
    const float fjx = frac[3u * j + 0u], fjy = frac[3u * j + 1u], fjz = frac[3u * j + 2u];

    // (fj - fi) + off  — same left-to-right order as the reference.
    const float dfx = fjx - fix;
    const float dfy = fjy - fiy;
    const float dfz = fjz - fiz;

    float* row = &tile[t * NIMG];

#pragma unroll
    for (int k = 0; k < NIMG; ++k) {
        // meshgrid(indexing="ij") order: (k/9, (k/3)%3, k%3) - 1 — compile-time.
        const float ox = (float)(k / 9 - 1);
        const float oy = (float)((k / 3) % 3 - 1);
        const float oz = (float)(k % 3 - 1);

        const float fx = dfx + ox;
        const float fy = dfy + oy;
        const float fz = dfz + oz;

        const float vx = fx * c00 + fy * c10 + fz * c20;
        const float vy = fx * c01 + fy * c11 + fz * c21;
        const float vz = fx * c02 + fy * c12 + fz * c22;

        const float d2 = vx * vx + vy * vy + vz * vz;
        // Mask from d2 only (bit-identical to ref); value from fast HW sqrt.
        const float d  = __builtin_amdgcn_sqrtf(d2);
        row[k] = (d2 > 1e-12f && d2 < 25.0f) ? d : 0.0f;
    }

    __syncthreads();

    // Coalesced float4 write-out of the block's flat 6912-float region.
    // Nontemporal: bypass L2/MALL write-allocate (streaming store).
    f32x4* out4 = (f32x4*)(out + (size_t)blockIdx.x * FLOATS_PER_BLOCK);
    const f32x4* tile4 = (const f32x4*)tile;
#pragma unroll
    for (int c = 0; c < 7; ++c) {
        const int l = c * 256 + (int)t;
        if (l < VEC4_PER_BLOCK) __builtin_nontemporal_store(tile4[l], &out4[l]);
    }
}

extern "C" void kernel_launch(void* const* d_in, const int* in_sizes, int n_in,
                              void* d_out, int out_size, void* d_ws, size_t ws_size,
                              hipStream_t stream) {
    const float* frac = (const float*)d_in[0];
    const float* cell = (const float*)d_in[1];
    float* out = (float*)d_out;

    const int grid = (NATOMS * NATOMS) / PAIRS_PER_BLOCK;  // 4096 blocks, exact
    PeriodicRadiusGraph_kernel<<<grid, PAIRS_PER_BLOCK, 0, stream>>>(frac, cell, out);
}